// Round 10
// baseline (177.801 us; speedup 1.0000x reference)
//
#include <hip/hip_runtime.h>
#include <hip/hip_bf16.h>
#include <math.h>

#define NN 325
#define FD 64
#define KH 4
#define DH 16
#define BT 192
#define NN2 (NN*NN)
#define PST (NN*DH)     // 5200 elems per (proj,head,bt) slice
#define WSL 5632        // per (h,bt) window slice: 11 windows * 512 el (also biasF slice)
#define HSTR 72         // ffn LDS stride (bf16)
#define NPROJ 975
#define NPB   325                        // proj blocks (ILP-3: b, b+325, b+650 — exact)
#define NBIAS 1848                       // 4*21*11*512 / 256 exactly
#define NPAD  (KH*BT)                    // 768 (now inside wpack)
#define ANB   1344                       // attn blocks: 5376 slots = 4*192*7, 3 q-tiles each
#define FNB   488                        // ffn blocks (ILP-2)
#define LOG2E 1.44269504088896f

typedef __attribute__((ext_vector_type(8))) short short8;
typedef __attribute__((ext_vector_type(4))) float f32x4;

union U8 { uint4 u; short8 s; ushort us[8]; };
__device__ inline short8 lds8(const ushort* p){ U8 t; t.u = *(const uint4*)p; return t.s; }
__device__ inline float b2f(ushort v){ return __uint_as_float(((unsigned)v) << 16); }
__device__ inline ushort f2b(float f){
  unsigned u = __float_as_uint(f);
  u += 0x7fff + ((u >> 16) & 1);
  return (ushort)(u >> 16);
}
__device__ inline unsigned pk2(float a, float b){
  union { __hip_bfloat162 h; unsigned u; } t;
  t.h = __float22bfloat162_rn(float2{a, b});
  return t.u;
}
__device__ inline short8 cvt8(const float* p){
  float4 u = ((const float4*)p)[0], v = ((const float4*)p)[1];
  U8 t;
  t.us[0]=f2b(u.x); t.us[1]=f2b(u.y); t.us[2]=f2b(u.z); t.us[3]=f2b(u.w);
  t.us[4]=f2b(v.x); t.us[5]=f2b(v.y); t.us[6]=f2b(v.z); t.us[7]=f2b(v.w);
  return t.s;
}

// ---------------- wpack: W's -> Wcat bf16 [448][64] + bcat | vt/kperm tail pad ----------------
__global__ __launch_bounds__(256) void wpack_kernel(
    const float* __restrict__ Wq,  const float* __restrict__ bq,
    const float* __restrict__ Wk,  const float* __restrict__ bk,
    const float* __restrict__ Wks, const float* __restrict__ bks,
    const float* __restrict__ Wv,  const float* __restrict__ bv,
    const float* __restrict__ Wvs, const float* __restrict__ bvs,
    const float* __restrict__ Wf1, const float* __restrict__ Wf2,
    ushort* __restrict__ Wcat, float* __restrict__ bcat,
    ushort* __restrict__ vt, ushort* __restrict__ kperm){
  int blk = blockIdx.x, tid = threadIdx.x;
  if (blk >= 7){
    // pad: zero tokens 325..351 (tt=10, w=5..31) in vt AND kperm for one (h,bt) slice
    int slice = blk - 7;
    if (tid < 432){
      int d = tid / 27, wz = 5 + tid % 27;
      vt[(size_t)slice * WSL + 5120 + d*32 + wz] = 0;
      int half = (wz >> 2) & 1, rr = 4*(wz >> 3) + (wz & 3);
      kperm[(size_t)slice * WSL + 5120 + half*256 + rr*16 + d] = 0;
    }
    return;
  }
  const float* Ws[7] = {Wq, Wk, Wks, Wv, Wvs, Wf1, Wf2};
  const float* bs[5] = {bq, bk, bks, bv, bvs};
  int f = blk * 64 + (tid >> 2);
  int c0 = (tid & 3) * 8;
  const float* wr = Ws[blk] + (f & 63) * 64;
  unsigned* dst = (unsigned*)Wcat + f * 32 + c0;
  #pragma unroll
  for (int c = 0; c < 8; ++c)
    dst[c] = f2b(wr[2*(c0+c)]) | ((unsigned)f2b(wr[2*(c0+c)+1]) << 16);
  if (blk < 5 && (tid & 3) == 0) bcat[f] = bs[blk][f & 63];
}

// ---------------- prep (ILP-3 over row-groups: b, b+325, b+650 — no guards) ----------------
// proj slots: Q 0-3 (scaled), KS 4-7, VS 8-11. K -> kperm [h][bt][tt][half][r16][d16]
// (token(r,half) = 8*(r>>2)+4*half+(r&3)); V -> vt [h][bt][tt][d16][w32];
// bias fp32 in MFMA C-lane layout: biasF [h][qt][tt][g4][m16][e8].
__global__ __launch_bounds__(256) void prep_kernel(
    const float* __restrict__ x, const ushort* __restrict__ Wcat,
    const float* __restrict__ bcat, ushort* __restrict__ proj,
    ushort* __restrict__ vt, ushort* __restrict__ kperm,
    const float* __restrict__ Wdi, const float* __restrict__ Wdo,
    const float* __restrict__ A,   const float* __restrict__ AT,
    float* __restrict__ biasF){
  int bid = blockIdx.x, tid = threadIdx.x;
  if (bid < NPB){
    int lane = tid & 63, wid = tid >> 6;
    int m = lane & 15, g = lane >> 4;
    int gra = (bid        ) * 64 + wid * 16 + m;
    int grb = (bid +   NPB) * 64 + wid * 16 + m;
    int grc = (bid + 2*NPB) * 64 + wid * 16 + m;
    int bta = gra / NN, na = gra - bta * NN;
    int btb = grb / NN, nb = grb - btb * NN;
    int btc = grc / NN, nc = grc - btc * NN;

    const float* xra = x + (size_t)gra * 64 + g * 8;
    const float* xrb = x + (size_t)grb * 64 + g * 8;
    const float* xrc = x + (size_t)grc * 64 + g * 8;
    short8 xa0 = cvt8(xra), xa1 = cvt8(xra + 32);
    short8 xb0 = cvt8(xrb), xb1 = cvt8(xrb + 32);
    short8 xc0 = cvt8(xrc), xc1 = cvt8(xrc + 32);

    for (int ct = 0; ct < 20; ++ct){
      short8 w0 = lds8(Wcat + ((size_t)(ct*16 + m) * 64 + g * 8));
      short8 w1 = lds8(Wcat + ((size_t)(ct*16 + m) * 64 + g * 8 + 32));
      float4 b4 = *(const float4*)(bcat + ct*16 + 4*g);
      f32x4 bc = {b4.x, b4.y, b4.z, b4.w};
      f32x4 accA = __builtin_amdgcn_mfma_f32_16x16x32_bf16(w0, xa0, bc, 0, 0, 0);
      accA = __builtin_amdgcn_mfma_f32_16x16x32_bf16(w1, xa1, accA, 0, 0, 0);
      f32x4 accB = __builtin_amdgcn_mfma_f32_16x16x32_bf16(w0, xb0, bc, 0, 0, 0);
      accB = __builtin_amdgcn_mfma_f32_16x16x32_bf16(w1, xb1, accB, 0, 0, 0);
      f32x4 accC = __builtin_amdgcn_mfma_f32_16x16x32_bf16(w0, xc0, bc, 0, 0, 0);
      accC = __builtin_amdgcn_mfma_f32_16x16x32_bf16(w1, xc1, accC, 0, 0, 0);
      if (ct >= 4 && ct < 8){
        #define KSTORE(NX, BTX, ACC)                                          \
        {                                                                     \
          int w = (NX) & 31;                                                  \
          ushort* kd = kperm + (size_t)((ct-4)*BT + (BTX)) * WSL              \
                     + ((NX) >> 5)*512 + ((w >> 2) & 1)*256                   \
                     + (4*(w >> 3) + (w & 3))*16 + 4*g;                       \
          uint2 wv; wv.x = pk2(ACC[0], ACC[1]); wv.y = pk2(ACC[2], ACC[3]);   \
          *(uint2*)kd = wv;                                                   \
        }
        KSTORE(na, bta, accA); KSTORE(nb, btb, accB); KSTORE(nc, btc, accC);
        #undef KSTORE
      } else if (ct >= 12 && ct < 16){
        #define VSTORE(NX, BTX, ACC)                                          \
        {                                                                     \
          ushort* vs = vt + (size_t)((ct-12)*BT + (BTX)) * WSL                \
                     + ((NX) >> 5)*512 + ((NX) & 31);                         \
          _Pragma("unroll")                                                   \
          for (int rg = 0; rg < 4; ++rg) vs[(4*g + rg) * 32] = f2b(ACC[rg]);  \
        }
        VSTORE(na, bta, accA); VSTORE(nb, btb, accB); VSTORE(nc, btc, accC);
        #undef VSTORE
      } else {
        int slot = (ct < 4) ? ct : (ct < 12 ? ct - 4 : ct - 8);
        float sc = (ct < 4) ? 0.25f * LOG2E : 1.0f;
        #define PSTORE(NX, BTX, ACC)                                          \
        {                                                                     \
          uint2 w2;                                                           \
          w2.x = pk2(ACC[0]*sc, ACC[1]*sc);                                   \
          w2.y = pk2(ACC[2]*sc, ACC[3]*sc);                                   \
          *(uint2*)(proj + ((size_t)slot * BT + (BTX)) * PST + (NX)*16 + 4*g) = w2; \
        }
        PSTORE(na, bta, accA); PSTORE(nb, btb, accB); PSTORE(nc, btc, accC);
        #undef PSTORE
      }
    }
  } else {
    // ---- bias fp32 C-lane layout; invalid -> -1e30 ----
    int idx = (bid - NPB) * 256 + tid;
    int h = idx / 118272;                  // 21*5632
    int rem = idx - h * 118272;
    int qt = rem / 5632;
    int r2 = rem - qt * 5632;
    int tt = r2 >> 9, r3 = r2 & 511;
    int gg = r3 >> 7, mm = (r3 >> 3) & 15, e8 = r3 & 7;
    int n = qt*16 + mm;
    int tok = tt*32 + gg*8 + e8;
    float s = -1e30f;
    if (n < NN && tok < NN){
      int ridx = n * NN + tok;
      s = 0.f;
      if (h < 2){
        #pragma unroll
        for (int k = 0; k < 3; ++k) s += Wdi[(h*3 + k)*NN2 + ridx] * A[k*NN2 + ridx];
      } else {
        int h2 = h - 2;
        #pragma unroll
        for (int k = 0; k < 3; ++k) s += Wdo[(h2*3 + k)*NN2 + ridx] * AT[k*NN2 + ridx];
      }
      s *= LOG2E;
    }
    biasF[idx] = s;
  }
}

// ---------------- attention: one wave per 3 q-tiles of one (h,bt); zero LDS ----------------
// 21 q-tiles = 3 x 7 exactly -> no ragged tail; every wave runs 3 full valid tiles.
// K/vT streams shared by all 3 tiles; bias enters as the MFMA C-operand; rowsum via
// MFMA against a ones-fragment.
__global__ __launch_bounds__(256, 3) void attn_kernel(
    const ushort* __restrict__ proj, const float* __restrict__ biasF,
    const ushort* __restrict__ vt, const ushort* __restrict__ kperm,
    ushort* __restrict__ val){
  int tid = threadIdx.x, lane = tid & 63, wid = tid >> 6;
  int bid = (int)blockIdx.x;
  int swz = (bid & 7) * (ANB/8) + (bid >> 3);   // contiguous range per XCD (1344%8==0)
  int p = swz * 4 + wid;                        // 5376 slots = 4*192*7
  int j = p % 7, bh = p / 7;
  int h = bh / BT, bt = bh - h * BT;
  int qt1 = 3*j, qt2 = 3*j + 1, qt3 = 3*j + 2;  // all < 21
  int m = lane & 15, g = lane >> 4;

  const ushort* qb  = proj + (size_t)((0*KH + h)*BT + bt) * PST;
  const ushort* ksb = proj + (size_t)((1*KH + h)*BT + bt) * PST;
  const ushort* vsb = proj + (size_t)((2*KH + h)*BT + bt) * PST;
  const ushort* ka  = kperm + (size_t)(h*BT + bt) * WSL + m*16 + (g&1)*8;
  const ushort* va  = vt    + (size_t)(h*BT + bt) * WSL + m*32 + g*8;
  const float*  b1a = biasF + (size_t)(h*21 + qt1) * WSL + g*128 + m*8;
  const float*  b2a = biasF + (size_t)(h*21 + qt2) * WSL + g*128 + m*8;
  const float*  b3a = biasF + (size_t)(h*21 + qt3) * WSL + g*128 + m*8;

  short8 zero = {0,0,0,0,0,0,0,0};
  // Q fragments; g>=2 zero so the k>=16 half of the QK MFMA contributes nothing
  short8 qf1 = (g < 2) ? lds8(qb + (size_t)(qt1*16 + m)*16 + (g&1)*8) : zero;
  short8 qf2 = (g < 2) ? lds8(qb + (size_t)(qt2*16 + m)*16 + (g&1)*8) : zero;
  short8 qf3 = (g < 2) ? lds8(qb + (size_t)(qt3*16 + m)*16 + (g&1)*8) : zero;

  // gate row loads issued early (dp math deferred to after the loop)
  int nb1 = min(qt1*16 + m, NN-1);
  int nb2 = min(qt2*16 + m, NN-1);
  int nb3 = min(qt3*16 + m, NN-1);
  uint2 qw1 = *(const uint2*)(qb  + (size_t)nb1*16 + g*4);
  uint2 kw1 = *(const uint2*)(ksb + (size_t)nb1*16 + g*4);
  uint2 qw2 = *(const uint2*)(qb  + (size_t)nb2*16 + g*4);
  uint2 kw2 = *(const uint2*)(ksb + (size_t)nb2*16 + g*4);
  uint2 qw3 = *(const uint2*)(qb  + (size_t)nb3*16 + g*4);
  uint2 kw3 = *(const uint2*)(ksb + (size_t)nb3*16 + g*4);

  // rotating depth-1 prefetch
  short8 kE = lds8(ka), kO = lds8(ka + 256), vv = lds8(va);
  f32x4 bE1 = *(const f32x4*)(b1a), bO1 = *(const f32x4*)(b1a + 4);
  f32x4 bE2 = *(const f32x4*)(b2a), bO2 = *(const f32x4*)(b2a + 4);
  f32x4 bE3 = *(const f32x4*)(b3a), bO3 = *(const f32x4*)(b3a + 4);

  short8 ones = {16256,16256,16256,16256,16256,16256,16256,16256}; // bf16 1.0 x8
  f32x4 o1 = {0.f,0.f,0.f,0.f}, o2 = {0.f,0.f,0.f,0.f}, o3 = {0.f,0.f,0.f,0.f};
  f32x4 r1 = {0.f,0.f,0.f,0.f}, r2 = {0.f,0.f,0.f,0.f}, r3 = {0.f,0.f,0.f,0.f};

  // per-tile fused step: S+bias via C-operand, exp2, pack, PV + rowsum
  #define TILE_STEP(QF, BE, BO, OO, RR)                                         \
  {                                                                             \
    f32x4 aE = __builtin_amdgcn_mfma_f32_16x16x32_bf16(kE, QF, BE, 0, 0, 0);    \
    f32x4 aO = __builtin_amdgcn_mfma_f32_16x16x32_bf16(kO, QF, BO, 0, 0, 0);    \
    float e0 = __builtin_amdgcn_exp2f(aE[0]);                                   \
    float e1 = __builtin_amdgcn_exp2f(aE[1]);                                   \
    float e2 = __builtin_amdgcn_exp2f(aE[2]);                                   \
    float e3 = __builtin_amdgcn_exp2f(aE[3]);                                   \
    float e4 = __builtin_amdgcn_exp2f(aO[0]);                                   \
    float e5 = __builtin_amdgcn_exp2f(aO[1]);                                   \
    float e6 = __builtin_amdgcn_exp2f(aO[2]);                                   \
    float e7 = __builtin_amdgcn_exp2f(aO[3]);                                   \
    U8 pf;                                                                      \
    pf.u.x = pk2(e0, e1); pf.u.y = pk2(e2, e3);                                 \
    pf.u.z = pk2(e4, e5); pf.u.w = pk2(e6, e7);                                 \
    OO = __builtin_amdgcn_mfma_f32_16x16x32_bf16(pf.s, vv,   OO, 0, 0, 0);      \
    RR = __builtin_amdgcn_mfma_f32_16x16x32_bf16(pf.s, ones, RR, 0, 0, 0);      \
  }

  #pragma unroll
  for (int tt = 0; tt < 11; ++tt){
    short8 kEn = zero, kOn = zero, vvn = zero;
    f32x4 bE1n = bE1, bO1n = bO1, bE2n = bE2, bO2n = bO2, bE3n = bE3, bO3n = bO3;
    if (tt < 10){
      const ushort* kan = ka + (tt+1)*512;
      kEn  = lds8(kan); kOn = lds8(kan + 256);
      vvn  = lds8(va + (tt+1)*512);
      bE1n = *(const f32x4*)(b1a + (tt+1)*512);
      bO1n = *(const f32x4*)(b1a + (tt+1)*512 + 4);
      bE2n = *(const f32x4*)(b2a + (tt+1)*512);
      bO2n = *(const f32x4*)(b2a + (tt+1)*512 + 4);
      bE3n = *(const f32x4*)(b3a + (tt+1)*512);
      bO3n = *(const f32x4*)(b3a + (tt+1)*512 + 4);
    }
    TILE_STEP(qf1, bE1, bO1, o1, r1);
    TILE_STEP(qf2, bE2, bO2, o2, r2);
    TILE_STEP(qf3, bE3, bO3, o3, r3);
    kE = kEn; kO = kOn; vv = vvn;
    bE1 = bE1n; bO1 = bO1n; bE2 = bE2n; bO2 = bO2n; bE3 = bE3n; bO3 = bO3n;
  }
  #undef TILE_STEP

  // ---- gate: dp per q=m, redistribute to q=4g+rg, sigmoid ----
  float dp1 = b2f((ushort)(qw1.x & 0xffff)) * b2f((ushort)(kw1.x & 0xffff))
            + b2f((ushort)(qw1.x >> 16))    * b2f((ushort)(kw1.x >> 16))
            + b2f((ushort)(qw1.y & 0xffff)) * b2f((ushort)(kw1.y & 0xffff))
            + b2f((ushort)(qw1.y >> 16))    * b2f((ushort)(kw1.y >> 16));
  float dp2 = b2f((ushort)(qw2.x & 0xffff)) * b2f((ushort)(kw2.x & 0xffff))
            + b2f((ushort)(qw2.x >> 16))    * b2f((ushort)(kw2.x >> 16))
            + b2f((ushort)(qw2.y & 0xffff)) * b2f((ushort)(kw2.y & 0xffff))
            + b2f((ushort)(qw2.y >> 16))    * b2f((ushort)(kw2.y >> 16));
  float dp3 = b2f((ushort)(qw3.x & 0xffff)) * b2f((ushort)(kw3.x & 0xffff))
            + b2f((ushort)(qw3.x >> 16))    * b2f((ushort)(kw3.x >> 16))
            + b2f((ushort)(qw3.y & 0xffff)) * b2f((ushort)(kw3.y & 0xffff))
            + b2f((ushort)(qw3.y >> 16))    * b2f((ushort)(kw3.y >> 16));
  dp1 += __shfl_xor(dp1, 16, 64); dp1 += __shfl_xor(dp1, 32, 64);
  dp2 += __shfl_xor(dp2, 16, 64); dp2 += __shfl_xor(dp2, 32, 64);
  dp3 += __shfl_xor(dp3, 16, 64); dp3 += __shfl_xor(dp3, 32, 64);
  int sb = g << 4;
  #pragma unroll
  for (int rg = 0; rg < 4; ++rg){
    float d1 = __uint_as_float(__builtin_amdgcn_ds_bpermute(sb + rg*4, __float_as_uint(dp1)));
    float d2 = __uint_as_float(__builtin_amdgcn_ds_bpermute(sb + rg*4, __float_as_uint(dp2)));
    float d3 = __uint_as_float(__builtin_amdgcn_ds_bpermute(sb + rg*4, __float_as_uint(dp3)));
    float es1 = __builtin_amdgcn_rcpf(1.f + __builtin_amdgcn_exp2f(-d1));
    float es2 = __builtin_amdgcn_rcpf(1.f + __builtin_amdgcn_exp2f(-d2));
    float es3 = __builtin_amdgcn_rcpf(1.f + __builtin_amdgcn_exp2f(-d3));
    int n1 = qt1*16 + 4*g + rg;
    int n2 = qt2*16 + 4*g + rg;
    int n3 = qt3*16 + 4*g + rg;
    float vsx1 = b2f(vsb[(size_t)min(n1, NN-1)*16 + m]);
    float vsx2 = b2f(vsb[(size_t)min(n2, NN-1)*16 + m]);
    float vsx3 = b2f(vsb[(size_t)min(n3, NN-1)*16 + m]);
    // out = (o + es*vs) / (es + rowsum)
    float iv1 = __builtin_amdgcn_rcpf(es1 + r1[rg]);
    float res1 = (o1[rg] + es1 * vsx1) * iv1;
    if (n1 < NN) val[((size_t)bt*NN + n1)*FD + h*16 + m] = f2b(res1);
    float iv2 = __builtin_amdgcn_rcpf(es2 + r2[rg]);
    float res2 = (o2[rg] + es2 * vsx2) * iv2;
    if (n2 < NN) val[((size_t)bt*NN + n2)*FD + h*16 + m] = f2b(res2);
    float iv3 = __builtin_amdgcn_rcpf(es3 + r3[rg]);
    float res3 = (o3[rg] + es3 * vsx3) * iv3;
    if (n3 < NN) val[((size_t)bt*NN + n3)*FD + h*16 + m] = f2b(res3);
  }
}

// ---------------- FFN + residual + LayerNorm (ILP-2: two row-groups per wave) ----------------
__global__ __launch_bounds__(256) void ffn_kernel(
    const ushort* __restrict__ val, const float* __restrict__ x,
    const ushort* __restrict__ Wf1b, const float* __restrict__ bf1,
    const ushort* __restrict__ Wf2b, const float* __restrict__ bf2,
    const float* __restrict__ g_ln, const float* __restrict__ b_ln,
    float* __restrict__ out){
  __shared__ ushort hs[4][2][16 * HSTR];   // wave-private slices x 2 groups
  int tid = threadIdx.x, lane = tid & 63, wid = tid >> 6;
  int m = lane & 15, g = lane >> 4;
  int bid = (int)blockIdx.x;
  int rowA = bid * 64 + wid * 16 + m;
  int bidB = bid + FNB;
  int bvB = (bidB < NPROJ);
  int rowB = bvB ? (bidB * 64 + wid * 16 + m) : rowA;

  short8 va0 = lds8(val + ((size_t)rowA * 64 + g * 8));
  short8 va1 = lds8(val + ((size_t)rowA * 64 + g * 8 + 32));
  short8 vb0 = lds8(val + ((size_t)rowB * 64 + g * 8));
  short8 vb1 = lds8(val + ((size_t)rowB * 64 + g * 8 + 32));

  #pragma unroll
  for (int ct = 0; ct < 4; ++ct){
    short8 w0 = lds8(Wf1b + ((size_t)(ct*16 + m) * 64 + g * 8));
    short8 w1 = lds8(Wf1b + ((size_t)(ct*16 + m) * 64 + g * 8 + 32));
    float4 b4 = *(const float4*)(bf1 + ct*16 + 4*g);
    f32x4 bc = {b4.x, b4.y, b4.z, b4.w};
    f32x4 aA = __builtin_amdgcn_mfma_f32_16x16x32_bf16(w0, va0, bc, 0, 0, 0);
    aA = __builtin_amdgcn_mfma_f32_16x16x32_bf16(w1, va1, aA, 0, 0, 0);
    f32x4 aB = __builtin_amdgcn_mfma_f32_16x16x32_bf16(w0, vb0, bc, 0, 0, 0);
    aB = __builtin_amdgcn_mfma_f32_16x16x32_bf16(w1, vb1, aB, 0, 0, 0);
    uint2 wA, wB;
    float a0 = 0.5f*aA[0]*(1.f + erff(aA[0]*0.70710678118654752f));
    float a1 = 0.5f*aA[1]*(1.f + erff(aA[1]*0.70710678118654752f));
    float a2 = 0.5f*aA[2]*(1.f + erff(aA[2]*0.70710678118654752f));
    float a3 = 0.5f*aA[3]*(1.f + erff(aA[3]*0.70710678118654752f));
    float c0 = 0.5f*aB[0]*(1.f + erff(aB[0]*0.70710678118654752f));
    float c1 = 0.5f*aB[1]*(1.f + erff(aB[1]*0.70710678118654752f));
    float c2 = 0.5f*aB[2]*(1.f + erff(aB[2]*0.70710678118654752f));
    float c3 = 0.5f*aB[3]*(1.f + erff(aB[3]*0.70710678118654752f));
    wA.x = pk2(a0, a1); wA.y = pk2(a2, a3);
    wB.x = pk2(c0, c1); wB.y = pk2(c2, c3);
    *(uint2*)&hs[wid][0][m * HSTR + ct*16 + 4*g] = wA;
    *(uint2*)&hs[wid][1][m * HSTR + ct*16 + 4*g] = wB;
  }
  asm volatile("s_waitcnt lgkmcnt(0)" ::: "memory");
  short8 hA0 = lds8(&hs[wid][0][m * HSTR + g * 8]);
  short8 hA1 = lds8(&hs[wid][0][m * HSTR + g * 8 + 32]);
  short8 hB0 = lds8(&hs[wid][1][m * HSTR + g * 8]);
  short8 hB1 = lds8(&hs[wid][1][m * HSTR + g * 8 + 32]);

  float tA[4][4], tB[4][4];
  #pragma unroll
  for (int ct = 0; ct < 4; ++ct){
    short8 w0 = lds8(Wf2b + ((size_t)(ct*16 + m) * 64 + g * 8));
    short8 w1 = lds8(Wf2b + ((size_t)(ct*16 + m) * 64 + g * 8 + 32));
    float4 b4 = *(const float4*)(bf2 + ct*16 + 4*g);
    f32x4 bc = {b4.x, b4.y, b4.z, b4.w};
    f32x4 aA = __builtin_amdgcn_mfma_f32_16x16x32_bf16(w0, hA0, bc, 0, 0, 0);
    aA = __builtin_amdgcn_mfma_f32_16x16x32_bf16(w1, hA1, aA, 0, 0, 0);
    f32x4 aB = __builtin_amdgcn_mfma_f32_16x16x32_bf16(w0, hB0, bc, 0, 0, 0);
    aB = __builtin_amdgcn_mfma_f32_16x16x32_bf16(w1, hB1, aB, 0, 0, 0);
    float4 xrA = *(const float4*)(x + (size_t)rowA * 64 + ct*16 + 4*g);
    float4 xrB = *(const float4*)(x + (size_t)rowB * 64 + ct*16 + 4*g);
    tA[ct][0] = aA[0] + xrA.x; tA[ct][1] = aA[1] + xrA.y;
    tA[ct][2] = aA[2] + xrA.z; tA[ct][3] = aA[3] + xrA.w;
    tB[ct][0] = aB[0] + xrB.x; tB[ct][1] = aB[1] + xrB.y;
    tB[ct][2] = aB[2] + xrB.z; tB[ct][3] = aB[3] + xrB.w;
  }
  float sA = 0.f, sB = 0.f;
  #pragma unroll
  for (int ct = 0; ct < 4; ++ct){
    sA += (tA[ct][0]+tA[ct][1]) + (tA[ct][2]+tA[ct][3]);
    sB += (tB[ct][0]+tB[ct][1]) + (tB[ct][2]+tB[ct][3]);
  }
  sA += __shfl_xor(sA, 16, 64); sA += __shfl_xor(sA, 32, 64);
  sB += __shfl_xor(sB, 16, 64); sB += __shfl_xor(sB, 32, 64);
  float muA = sA * (1.f/64.f), muB = sB * (1.f/64.f);
  float vA = 0.f, vB = 0.f;
  #pragma unroll
  for (int ct = 0; ct < 4; ++ct){
    #pragma unroll
    for (int rg = 0; rg < 4; ++rg){
      float dA = tA[ct][rg] - muA; vA += dA*dA;
      float dB = tB[ct][rg] - muB; vB += dB*dB;
    }
  }
  vA += __shfl_xor(vA, 16, 64); vA += __shfl_xor(vA, 32, 64);
  vB += __shfl_xor(vB, 16, 64); vB += __shfl_xor(vB, 32, 64);
  float rsA = rsqrtf(vA * (1.f/64.f) + 1e-5f);
  float rsB = rsqrtf(vB * (1.f/64.f) + 1e-5f);
  #pragma unroll
  for (int ct = 0; ct < 4; ++ct){
    float4 g4 = *(const float4*)(g_ln + ct*16 + 4*g);
    float4 bb = *(const float4*)(b_ln + ct*16 + 4*g);
    float4 oA;
    oA.x = g4.x*(tA[ct][0]-muA)*rsA + bb.x;
    oA.y = g4.y*(tA[ct][1]-muA)*rsA + bb.y;
    oA.z = g4.z*(tA[ct][2]-muA)*rsA + bb.z;
    oA.w = g4.w*(tA[ct][3]-muA)*rsA + bb.w;
    *(float4*)(out + (size_t)rowA * 64 + ct*16 + 4*g) = oA;
    if (bvB){
      float4 oB;
      oB.x = g4.x*(tB[ct][0]-muB)*rsB + bb.x;
      oB.y = g4.y*(tB[ct][1]-muB)*rsB + bb.y;
      oB.z = g4.z*(tB[ct][2]-muB)*rsB + bb.z;
      oB.w = g4.w*(tB[ct][3]-muB)*rsB + bb.w;
      *(float4*)(out + (size_t)rowB * 64 + ct*16 + 4*g) = oB;
    }
  }
}

extern "C" void kernel_launch(void* const* d_in, const int* in_sizes, int n_in,
                              void* d_out, int out_size, void* d_ws, size_t ws_size,
                              hipStream_t stream) {
  const float* x    = (const float*)d_in[0];
  const float* A    = (const float*)d_in[1];
  const float* AT   = (const float*)d_in[2];
  const float* Wq   = (const float*)d_in[3];
  const float* bq   = (const float*)d_in[4];
  const float* Wk   = (const float*)d_in[5];
  const float* bk   = (const float*)d_in[6];
  const float* Wks  = (const float*)d_in[7];
  const float* bks  = (const float*)d_in[8];
  const float* Wv   = (const float*)d_in[9];
  const float* bv   = (const float*)d_in[10];
  const float* Wvs  = (const float*)d_in[11];
  const float* bvs  = (const float*)d_in[12];
  const float* Wdi  = (const float*)d_in[13];
  const float* Wdo  = (const float*)d_in[14];
  const float* Wf1  = (const float*)d_in[15];
  const float* bf1  = (const float*)d_in[16];
  const float* Wf2  = (const float*)d_in[17];
  const float* bf2  = (const float*)d_in[18];
  const float* g_ln = (const float*)d_in[19];
  const float* b_ln = (const float*)d_in[20];
  float* out = (float*)d_out;

  float* ws = (float*)d_ws;
  ushort* proj  = (ushort*)ws;                     // 12 slots (Q,KS,VS): 11,980,800 ush
  float*  biasF = ws + 5990400;                    // 473,088 f [4][21][11][4][16][8]
  ushort* val   = (ushort*)(ws + 6463488);         // 3,993,600 ush
  ushort* vt    = (ushort*)(ws + 8460288);         // 4,325,376 ush [4][192][11][16][32]
  ushort* kperm = (ushort*)(ws + 10622976);        // 4,325,376 ush [4][192][11][2][16][16]
  ushort* Wcat  = (ushort*)(ws + 12785664);        // 28,672 ush
  float*  bcat  = ws + 12800000;                   // 320 f
  ushort* Wf1b  = Wcat + 320*64;
  ushort* Wf2b  = Wcat + 384*64;

  wpack_kernel<<<7 + NPAD, 256, 0, stream>>>(Wq, bq, Wk, bk, Wks, bks,
                                             Wv, bv, Wvs, bvs, Wf1, Wf2,
                                             Wcat, bcat, vt, kperm);
  prep_kernel<<<NPB + NBIAS, 256, 0, stream>>>(
      x, Wcat, bcat, proj, vt, kperm, Wdi, Wdo, A, AT, biasF);
  attn_kernel<<<ANB, 256, 0, stream>>>(proj, biasF, vt, kperm, val);
  ffn_kernel<<<FNB, 256, 0, stream>>>(val, x, Wf1b, bf1, Wf2b, bf2,
                                      g_ln, b_ln, out);
}

// Round 11
// 172.449 us; speedup vs baseline: 1.0310x; 1.0310x over previous
//
#include <hip/hip_runtime.h>
#include <hip/hip_bf16.h>
#include <math.h>

#define NN 325
#define FD 64
#define KH 4
#define DH 16
#define BT 192
#define NN2 (NN*NN)
#define PST (NN*DH)     // 5200 elems per (proj,head,bt) slice
#define WSL 5632        // per (h,bt) window slice: 11 windows * 512 el (also biasF slice)
#define HSTR 72         // ffn LDS stride (bf16)
#define NPROJ 975
#define NPB   488                        // proj blocks (ILP-2: block b also does b+488)
#define NBIAS 1848                       // 4*21*11*512 / 256 exactly
#define NPAD  (KH*BT)                    // 768
#define ANB   1344                       // attn blocks: 5376 slots = 4*192*7, 3 q-tiles each
#define FNB   488                        // ffn blocks (ILP-2)
#define LOG2E 1.44269504088896f

typedef __attribute__((ext_vector_type(8))) short short8;
typedef __attribute__((ext_vector_type(4))) float f32x4;

union U8 { uint4 u; short8 s; ushort us[8]; };
__device__ inline short8 lds8(const ushort* p){ U8 t; t.u = *(const uint4*)p; return t.s; }
__device__ inline float b2f(ushort v){ return __uint_as_float(((unsigned)v) << 16); }
__device__ inline ushort f2b(float f){
  unsigned u = __float_as_uint(f);
  u += 0x7fff + ((u >> 16) & 1);
  return (ushort)(u >> 16);
}
__device__ inline unsigned pk2(float a, float b){
  union { __hip_bfloat162 h; unsigned u; } t;
  t.h = __float22bfloat162_rn(float2{a, b});
  return t.u;
}
__device__ inline short8 cvt8(const float* p){
  float4 u = ((const float4*)p)[0], v = ((const float4*)p)[1];
  U8 t;
  t.us[0]=f2b(u.x); t.us[1]=f2b(u.y); t.us[2]=f2b(u.z); t.us[3]=f2b(u.w);
  t.us[4]=f2b(v.x); t.us[5]=f2b(v.y); t.us[6]=f2b(v.z); t.us[7]=f2b(v.w);
  return t.s;
}

// ---------------- wpack: W's -> Wcat bf16 [448][64] + bcat ----------------
__global__ __launch_bounds__(256) void wpack_kernel(
    const float* __restrict__ Wq,  const float* __restrict__ bq,
    const float* __restrict__ Wk,  const float* __restrict__ bk,
    const float* __restrict__ Wks, const float* __restrict__ bks,
    const float* __restrict__ Wv,  const float* __restrict__ bv,
    const float* __restrict__ Wvs, const float* __restrict__ bvs,
    const float* __restrict__ Wf1, const float* __restrict__ Wf2,
    ushort* __restrict__ Wcat, float* __restrict__ bcat){
  int blk = blockIdx.x;
  const float* Ws[7] = {Wq, Wk, Wks, Wv, Wvs, Wf1, Wf2};
  const float* bs[5] = {bq, bk, bks, bv, bvs};
  int f = blk * 64 + (threadIdx.x >> 2);
  int c0 = (threadIdx.x & 3) * 8;
  const float* wr = Ws[blk] + (f & 63) * 64;
  unsigned* dst = (unsigned*)Wcat + f * 32 + c0;
  #pragma unroll
  for (int c = 0; c < 8; ++c)
    dst[c] = f2b(wr[2*(c0+c)]) | ((unsigned)f2b(wr[2*(c0+c)+1]) << 16);
  if (blk < 5 && (threadIdx.x & 3) == 0) bcat[f] = bs[blk][f & 63];
}

// ---------------- prep (R7 structure: ILP-2 over row-groups) ----------------
// proj slots: Q 0-3 (scaled), KS 4-7, VS 8-11. K -> kperm [h][bt][tt][half][r16][d16]
// (token(r,half) = 8*(r>>2)+4*half+(r&3)); V -> vt [h][bt][tt][d16][w32];
// bias fp32 in MFMA C-lane layout: biasF [h][qt][tt][g4][m16][e8].
__global__ __launch_bounds__(256) void prep_kernel(
    const float* __restrict__ x, const ushort* __restrict__ Wcat,
    const float* __restrict__ bcat, ushort* __restrict__ proj,
    ushort* __restrict__ vt, ushort* __restrict__ kperm,
    const float* __restrict__ Wdi, const float* __restrict__ Wdo,
    const float* __restrict__ A,   const float* __restrict__ AT,
    float* __restrict__ biasF){
  int bid = blockIdx.x, tid = threadIdx.x;
  if (bid < NPB){
    int lane = tid & 63, wid = tid >> 6;
    int m = lane & 15, g = lane >> 4;
    int gra = (bid * 64) + wid * 16 + m;
    int bta = gra / NN, na = gra - bta * NN;
    int bidB = bid + NPB;
    int bvB = (bidB < NPROJ);
    int grb = bvB ? (bidB * 64 + wid * 16 + m) : gra;
    int btb = grb / NN, nb = grb - btb * NN;

    const float* xra = x + (size_t)gra * 64 + g * 8;
    const float* xrb = x + (size_t)grb * 64 + g * 8;
    short8 xa0 = cvt8(xra), xa1 = cvt8(xra + 32);
    short8 xb0 = cvt8(xrb), xb1 = cvt8(xrb + 32);

    for (int ct = 0; ct < 20; ++ct){
      short8 w0 = lds8(Wcat + ((size_t)(ct*16 + m) * 64 + g * 8));
      short8 w1 = lds8(Wcat + ((size_t)(ct*16 + m) * 64 + g * 8 + 32));
      float4 b4 = *(const float4*)(bcat + ct*16 + 4*g);
      f32x4 bc = {b4.x, b4.y, b4.z, b4.w};
      f32x4 accA = __builtin_amdgcn_mfma_f32_16x16x32_bf16(w0, xa0, bc, 0, 0, 0);
      accA = __builtin_amdgcn_mfma_f32_16x16x32_bf16(w1, xa1, accA, 0, 0, 0);
      f32x4 accB = __builtin_amdgcn_mfma_f32_16x16x32_bf16(w0, xb0, bc, 0, 0, 0);
      accB = __builtin_amdgcn_mfma_f32_16x16x32_bf16(w1, xb1, accB, 0, 0, 0);
      if (ct >= 4 && ct < 8){
        {
          int w = na & 31;
          ushort* kd = kperm + (size_t)((ct-4)*BT + bta) * WSL
                     + (na >> 5)*512 + ((w >> 2) & 1)*256
                     + (4*(w >> 3) + (w & 3))*16 + 4*g;
          uint2 wv; wv.x = pk2(accA[0], accA[1]); wv.y = pk2(accA[2], accA[3]);
          *(uint2*)kd = wv;
        }
        if (bvB){
          int w = nb & 31;
          ushort* kd = kperm + (size_t)((ct-4)*BT + btb) * WSL
                     + (nb >> 5)*512 + ((w >> 2) & 1)*256
                     + (4*(w >> 3) + (w & 3))*16 + 4*g;
          uint2 wv; wv.x = pk2(accB[0], accB[1]); wv.y = pk2(accB[2], accB[3]);
          *(uint2*)kd = wv;
        }
      } else if (ct >= 12 && ct < 16){
        {
          ushort* vs = vt + (size_t)((ct-12)*BT + bta) * WSL + (na >> 5)*512 + (na & 31);
          #pragma unroll
          for (int rg = 0; rg < 4; ++rg)
            vs[(4*g + rg) * 32] = f2b(accA[rg]);
        }
        if (bvB){
          ushort* vs = vt + (size_t)((ct-12)*BT + btb) * WSL + (nb >> 5)*512 + (nb & 31);
          #pragma unroll
          for (int rg = 0; rg < 4; ++rg)
            vs[(4*g + rg) * 32] = f2b(accB[rg]);
        }
      } else {
        int slot = (ct < 4) ? ct : (ct < 12 ? ct - 4 : ct - 8);
        float sc = (ct < 4) ? 0.25f * LOG2E : 1.0f;
        {
          uint2 w2;
          w2.x = pk2(accA[0]*sc, accA[1]*sc);
          w2.y = pk2(accA[2]*sc, accA[3]*sc);
          *(uint2*)(proj + ((size_t)slot * BT + bta) * PST + na*16 + 4*g) = w2;
        }
        if (bvB){
          uint2 w2;
          w2.x = pk2(accB[0]*sc, accB[1]*sc);
          w2.y = pk2(accB[2]*sc, accB[3]*sc);
          *(uint2*)(proj + ((size_t)slot * BT + btb) * PST + nb*16 + 4*g) = w2;
        }
      }
    }
  } else if (bid < NPB + NBIAS){
    // ---- bias fp32 C-lane layout; invalid -> -1e30 ----
    int idx = (bid - NPB) * 256 + tid;
    int h = idx / 118272;                  // 21*5632
    int rem = idx - h * 118272;
    int qt = rem / 5632;
    int r2 = rem - qt * 5632;
    int tt = r2 >> 9, r3 = r2 & 511;
    int gg = r3 >> 7, mm = (r3 >> 3) & 15, e8 = r3 & 7;
    int n = qt*16 + mm;
    int tok = tt*32 + gg*8 + e8;
    float s = -1e30f;
    if (n < NN && tok < NN){
      int ridx = n * NN + tok;
      s = 0.f;
      if (h < 2){
        #pragma unroll
        for (int k = 0; k < 3; ++k) s += Wdi[(h*3 + k)*NN2 + ridx] * A[k*NN2 + ridx];
      } else {
        int h2 = h - 2;
        #pragma unroll
        for (int k = 0; k < 3; ++k) s += Wdo[(h2*3 + k)*NN2 + ridx] * AT[k*NN2 + ridx];
      }
      s *= LOG2E;
    }
    biasF[idx] = s;
  } else {
    // ---- pad: zero tokens 325..351 (tt=10, w=5..31) in vt AND kperm ----
    int slice = bid - NPB - NBIAS;
    if (tid < 432){
      int d = tid / 27, wz = 5 + tid % 27;
      vt[(size_t)slice * WSL + 5120 + d*32 + wz] = 0;
      int half = (wz >> 2) & 1, rr = 4*(wz >> 3) + (wz & 3);
      kperm[(size_t)slice * WSL + 5120 + half*256 + rr*16 + d] = 0;
    }
  }
}

// ---------------- attention: one wave per 3 q-tiles of one (h,bt); zero LDS ----------------
// 21 q-tiles = 3 x 7 exactly -> no ragged tail; every wave runs 3 full valid tiles.
// K/vT streams shared by all 3 tiles (re-read by 7 slots instead of 11); bias enters
// as the MFMA C-operand; rowsum via MFMA against a ones-fragment.
__global__ __launch_bounds__(256, 3) void attn_kernel(
    const ushort* __restrict__ proj, const float* __restrict__ biasF,
    const ushort* __restrict__ vt, const ushort* __restrict__ kperm,
    ushort* __restrict__ val){
  int tid = threadIdx.x, lane = tid & 63, wid = tid >> 6;
  int bid = (int)blockIdx.x;
  int swz = (bid & 7) * (ANB/8) + (bid >> 3);   // contiguous range per XCD (1344%8==0)
  int p = swz * 4 + wid;                        // 5376 slots = 4*192*7
  int j = p % 7, bh = p / 7;
  int h = bh / BT, bt = bh - h * BT;
  int qt1 = 3*j, qt2 = 3*j + 1, qt3 = 3*j + 2;  // all < 21
  int m = lane & 15, g = lane >> 4;

  const ushort* qb  = proj + (size_t)((0*KH + h)*BT + bt) * PST;
  const ushort* ksb = proj + (size_t)((1*KH + h)*BT + bt) * PST;
  const ushort* vsb = proj + (size_t)((2*KH + h)*BT + bt) * PST;
  const ushort* ka  = kperm + (size_t)(h*BT + bt) * WSL + m*16 + (g&1)*8;
  const ushort* va  = vt    + (size_t)(h*BT + bt) * WSL + m*32 + g*8;
  const float*  b1a = biasF + (size_t)(h*21 + qt1) * WSL + g*128 + m*8;
  const float*  b2a = biasF + (size_t)(h*21 + qt2) * WSL + g*128 + m*8;
  const float*  b3a = biasF + (size_t)(h*21 + qt3) * WSL + g*128 + m*8;

  short8 zero = {0,0,0,0,0,0,0,0};
  // Q fragments; g>=2 zero so the k>=16 half of the QK MFMA contributes nothing
  short8 qf1 = (g < 2) ? lds8(qb + (size_t)(qt1*16 + m)*16 + (g&1)*8) : zero;
  short8 qf2 = (g < 2) ? lds8(qb + (size_t)(qt2*16 + m)*16 + (g&1)*8) : zero;
  short8 qf3 = (g < 2) ? lds8(qb + (size_t)(qt3*16 + m)*16 + (g&1)*8) : zero;

  // gate row loads issued early (dp math deferred to after the loop)
  int nb1 = min(qt1*16 + m, NN-1);
  int nb2 = min(qt2*16 + m, NN-1);
  int nb3 = min(qt3*16 + m, NN-1);
  uint2 qw1 = *(const uint2*)(qb  + (size_t)nb1*16 + g*4);
  uint2 kw1 = *(const uint2*)(ksb + (size_t)nb1*16 + g*4);
  uint2 qw2 = *(const uint2*)(qb  + (size_t)nb2*16 + g*4);
  uint2 kw2 = *(const uint2*)(ksb + (size_t)nb2*16 + g*4);
  uint2 qw3 = *(const uint2*)(qb  + (size_t)nb3*16 + g*4);
  uint2 kw3 = *(const uint2*)(ksb + (size_t)nb3*16 + g*4);

  // rotating depth-1 prefetch
  short8 kE = lds8(ka), kO = lds8(ka + 256), vv = lds8(va);
  f32x4 bE1 = *(const f32x4*)(b1a), bO1 = *(const f32x4*)(b1a + 4);
  f32x4 bE2 = *(const f32x4*)(b2a), bO2 = *(const f32x4*)(b2a + 4);
  f32x4 bE3 = *(const f32x4*)(b3a), bO3 = *(const f32x4*)(b3a + 4);

  short8 ones = {16256,16256,16256,16256,16256,16256,16256,16256}; // bf16 1.0 x8
  f32x4 o1 = {0.f,0.f,0.f,0.f}, o2 = {0.f,0.f,0.f,0.f}, o3 = {0.f,0.f,0.f,0.f};
  f32x4 r1 = {0.f,0.f,0.f,0.f}, r2 = {0.f,0.f,0.f,0.f}, r3 = {0.f,0.f,0.f,0.f};

  // per-tile fused step: S+bias via C-operand, exp2, pack, PV + rowsum
  #define TILE_STEP(QF, BE, BO, OO, RR)                                         \
  {                                                                             \
    f32x4 aE = __builtin_amdgcn_mfma_f32_16x16x32_bf16(kE, QF, BE, 0, 0, 0);    \
    f32x4 aO = __builtin_amdgcn_mfma_f32_16x16x32_bf16(kO, QF, BO, 0, 0, 0);    \
    float e0 = __builtin_amdgcn_exp2f(aE[0]);                                   \
    float e1 = __builtin_amdgcn_exp2f(aE[1]);                                   \
    float e2 = __builtin_amdgcn_exp2f(aE[2]);                                   \
    float e3 = __builtin_amdgcn_exp2f(aE[3]);                                   \
    float e4 = __builtin_amdgcn_exp2f(aO[0]);                                   \
    float e5 = __builtin_amdgcn_exp2f(aO[1]);                                   \
    float e6 = __builtin_amdgcn_exp2f(aO[2]);                                   \
    float e7 = __builtin_amdgcn_exp2f(aO[3]);                                   \
    U8 pf;                                                                      \
    pf.u.x = pk2(e0, e1); pf.u.y = pk2(e2, e3);                                 \
    pf.u.z = pk2(e4, e5); pf.u.w = pk2(e6, e7);                                 \
    OO = __builtin_amdgcn_mfma_f32_16x16x32_bf16(pf.s, vv,   OO, 0, 0, 0);      \
    RR = __builtin_amdgcn_mfma_f32_16x16x32_bf16(pf.s, ones, RR, 0, 0, 0);      \
  }

  #pragma unroll
  for (int tt = 0; tt < 11; ++tt){
    short8 kEn = zero, kOn = zero, vvn = zero;
    f32x4 bE1n = bE1, bO1n = bO1, bE2n = bE2, bO2n = bO2, bE3n = bE3, bO3n = bO3;
    if (tt < 10){
      const ushort* kan = ka + (tt+1)*512;
      kEn  = lds8(kan); kOn = lds8(kan + 256);
      vvn  = lds8(va + (tt+1)*512);
      bE1n = *(const f32x4*)(b1a + (tt+1)*512);
      bO1n = *(const f32x4*)(b1a + (tt+1)*512 + 4);
      bE2n = *(const f32x4*)(b2a + (tt+1)*512);
      bO2n = *(const f32x4*)(b2a + (tt+1)*512 + 4);
      bE3n = *(const f32x4*)(b3a + (tt+1)*512);
      bO3n = *(const f32x4*)(b3a + (tt+1)*512 + 4);
    }
    TILE_STEP(qf1, bE1, bO1, o1, r1);
    TILE_STEP(qf2, bE2, bO2, o2, r2);
    TILE_STEP(qf3, bE3, bO3, o3, r3);
    kE = kEn; kO = kOn; vv = vvn;
    bE1 = bE1n; bO1 = bO1n; bE2 = bE2n; bO2 = bO2n; bE3 = bE3n; bO3 = bO3n;
  }
  #undef TILE_STEP

  // ---- gate: dp per q=m, redistribute to q=4g+rg, sigmoid ----
  float dp1 = b2f((ushort)(qw1.x & 0xffff)) * b2f((ushort)(kw1.x & 0xffff))
            + b2f((ushort)(qw1.x >> 16))    * b2f((ushort)(kw1.x >> 16))
            + b2f((ushort)(qw1.y & 0xffff)) * b2f((ushort)(kw1.y & 0xffff))
            + b2f((ushort)(qw1.y >> 16))    * b2f((ushort)(kw1.y >> 16));
  float dp2 = b2f((ushort)(qw2.x & 0xffff)) * b2f((ushort)(kw2.x & 0xffff))
            + b2f((ushort)(qw2.x >> 16))    * b2f((ushort)(kw2.x >> 16))
            + b2f((ushort)(qw2.y & 0xffff)) * b2f((ushort)(kw2.y & 0xffff))
            + b2f((ushort)(qw2.y >> 16))    * b2f((ushort)(kw2.y >> 16));
  float dp3 = b2f((ushort)(qw3.x & 0xffff)) * b2f((ushort)(kw3.x & 0xffff))
            + b2f((ushort)(qw3.x >> 16))    * b2f((ushort)(kw3.x >> 16))
            + b2f((ushort)(qw3.y & 0xffff)) * b2f((ushort)(kw3.y & 0xffff))
            + b2f((ushort)(qw3.y >> 16))    * b2f((ushort)(kw3.y >> 16));
  dp1 += __shfl_xor(dp1, 16, 64); dp1 += __shfl_xor(dp1, 32, 64);
  dp2 += __shfl_xor(dp2, 16, 64); dp2 += __shfl_xor(dp2, 32, 64);
  dp3 += __shfl_xor(dp3, 16, 64); dp3 += __shfl_xor(dp3, 32, 64);
  int sb = g << 4;
  #pragma unroll
  for (int rg = 0; rg < 4; ++rg){
    float d1 = __uint_as_float(__builtin_amdgcn_ds_bpermute(sb + rg*4, __float_as_uint(dp1)));
    float d2 = __uint_as_float(__builtin_amdgcn_ds_bpermute(sb + rg*4, __float_as_uint(dp2)));
    float d3 = __uint_as_float(__builtin_amdgcn_ds_bpermute(sb + rg*4, __float_as_uint(dp3)));
    float es1 = __builtin_amdgcn_rcpf(1.f + __builtin_amdgcn_exp2f(-d1));
    float es2 = __builtin_amdgcn_rcpf(1.f + __builtin_amdgcn_exp2f(-d2));
    float es3 = __builtin_amdgcn_rcpf(1.f + __builtin_amdgcn_exp2f(-d3));
    int n1 = qt1*16 + 4*g + rg;
    int n2 = qt2*16 + 4*g + rg;
    int n3 = qt3*16 + 4*g + rg;
    float vsx1 = b2f(vsb[(size_t)min(n1, NN-1)*16 + m]);
    float vsx2 = b2f(vsb[(size_t)min(n2, NN-1)*16 + m]);
    float vsx3 = b2f(vsb[(size_t)min(n3, NN-1)*16 + m]);
    // out = (o + es*vs) / (es + rowsum)
    float iv1 = __builtin_amdgcn_rcpf(es1 + r1[rg]);
    float res1 = (o1[rg] + es1 * vsx1) * iv1;
    if (n1 < NN) val[((size_t)bt*NN + n1)*FD + h*16 + m] = f2b(res1);
    float iv2 = __builtin_amdgcn_rcpf(es2 + r2[rg]);
    float res2 = (o2[rg] + es2 * vsx2) * iv2;
    if (n2 < NN) val[((size_t)bt*NN + n2)*FD + h*16 + m] = f2b(res2);
    float iv3 = __builtin_amdgcn_rcpf(es3 + r3[rg]);
    float res3 = (o3[rg] + es3 * vsx3) * iv3;
    if (n3 < NN) val[((size_t)bt*NN + n3)*FD + h*16 + m] = f2b(res3);
  }
}

// ---------------- FFN + residual + LayerNorm (ILP-2: two row-groups per wave) ----------------
__global__ __launch_bounds__(256) void ffn_kernel(
    const ushort* __restrict__ val, const float* __restrict__ x,
    const ushort* __restrict__ Wf1b, const float* __restrict__ bf1,
    const ushort* __restrict__ Wf2b, const float* __restrict__ bf2,
    const float* __restrict__ g_ln, const float* __restrict__ b_ln,
    float* __restrict__ out){
  __shared__ ushort hs[4][2][16 * HSTR];   // wave-private slices x 2 groups
  int tid = threadIdx.x, lane = tid & 63, wid = tid >> 6;
  int m = lane & 15, g = lane >> 4;
  int bid = (int)blockIdx.x;
  int rowA = bid * 64 + wid * 16 + m;
  int bidB = bid + FNB;
  int bvB = (bidB < NPROJ);
  int rowB = bvB ? (bidB * 64 + wid * 16 + m) : rowA;

  short8 va0 = lds8(val + ((size_t)rowA * 64 + g * 8));
  short8 va1 = lds8(val + ((size_t)rowA * 64 + g * 8 + 32));
  short8 vb0 = lds8(val + ((size_t)rowB * 64 + g * 8));
  short8 vb1 = lds8(val + ((size_t)rowB * 64 + g * 8 + 32));

  #pragma unroll
  for (int ct = 0; ct < 4; ++ct){
    short8 w0 = lds8(Wf1b + ((size_t)(ct*16 + m) * 64 + g * 8));
    short8 w1 = lds8(Wf1b + ((size_t)(ct*16 + m) * 64 + g * 8 + 32));
    float4 b4 = *(const float4*)(bf1 + ct*16 + 4*g);
    f32x4 bc = {b4.x, b4.y, b4.z, b4.w};
    f32x4 aA = __builtin_amdgcn_mfma_f32_16x16x32_bf16(w0, va0, bc, 0, 0, 0);
    aA = __builtin_amdgcn_mfma_f32_16x16x32_bf16(w1, va1, aA, 0, 0, 0);
    f32x4 aB = __builtin_amdgcn_mfma_f32_16x16x32_bf16(w0, vb0, bc, 0, 0, 0);
    aB = __builtin_amdgcn_mfma_f32_16x16x32_bf16(w1, vb1, aB, 0, 0, 0);
    uint2 wA, wB;
    float a0 = 0.5f*aA[0]*(1.f + erff(aA[0]*0.70710678118654752f));
    float a1 = 0.5f*aA[1]*(1.f + erff(aA[1]*0.70710678118654752f));
    float a2 = 0.5f*aA[2]*(1.f + erff(aA[2]*0.70710678118654752f));
    float a3 = 0.5f*aA[3]*(1.f + erff(aA[3]*0.70710678118654752f));
    float c0 = 0.5f*aB[0]*(1.f + erff(aB[0]*0.70710678118654752f));
    float c1 = 0.5f*aB[1]*(1.f + erff(aB[1]*0.70710678118654752f));
    float c2 = 0.5f*aB[2]*(1.f + erff(aB[2]*0.70710678118654752f));
    float c3 = 0.5f*aB[3]*(1.f + erff(aB[3]*0.70710678118654752f));
    wA.x = pk2(a0, a1); wA.y = pk2(a2, a3);
    wB.x = pk2(c0, c1); wB.y = pk2(c2, c3);
    *(uint2*)&hs[wid][0][m * HSTR + ct*16 + 4*g] = wA;
    *(uint2*)&hs[wid][1][m * HSTR + ct*16 + 4*g] = wB;
  }
  asm volatile("s_waitcnt lgkmcnt(0)" ::: "memory");
  short8 hA0 = lds8(&hs[wid][0][m * HSTR + g * 8]);
  short8 hA1 = lds8(&hs[wid][0][m * HSTR + g * 8 + 32]);
  short8 hB0 = lds8(&hs[wid][1][m * HSTR + g * 8]);
  short8 hB1 = lds8(&hs[wid][1][m * HSTR + g * 8 + 32]);

  float tA[4][4], tB[4][4];
  #pragma unroll
  for (int ct = 0; ct < 4; ++ct){
    short8 w0 = lds8(Wf2b + ((size_t)(ct*16 + m) * 64 + g * 8));
    short8 w1 = lds8(Wf2b + ((size_t)(ct*16 + m) * 64 + g * 8 + 32));
    float4 b4 = *(const float4*)(bf2 + ct*16 + 4*g);
    f32x4 bc = {b4.x, b4.y, b4.z, b4.w};
    f32x4 aA = __builtin_amdgcn_mfma_f32_16x16x32_bf16(w0, hA0, bc, 0, 0, 0);
    aA = __builtin_amdgcn_mfma_f32_16x16x32_bf16(w1, hA1, aA, 0, 0, 0);
    f32x4 aB = __builtin_amdgcn_mfma_f32_16x16x32_bf16(w0, hB0, bc, 0, 0, 0);
    aB = __builtin_amdgcn_mfma_f32_16x16x32_bf16(w1, hB1, aB, 0, 0, 0);
    float4 xrA = *(const float4*)(x + (size_t)rowA * 64 + ct*16 + 4*g);
    float4 xrB = *(const float4*)(x + (size_t)rowB * 64 + ct*16 + 4*g);
    tA[ct][0] = aA[0] + xrA.x; tA[ct][1] = aA[1] + xrA.y;
    tA[ct][2] = aA[2] + xrA.z; tA[ct][3] = aA[3] + xrA.w;
    tB[ct][0] = aB[0] + xrB.x; tB[ct][1] = aB[1] + xrB.y;
    tB[ct][2] = aB[2] + xrB.z; tB[ct][3] = aB[3] + xrB.w;
  }
  float sA = 0.f, sB = 0.f;
  #pragma unroll
  for (int ct = 0; ct < 4; ++ct){
    sA += (tA[ct][0]+tA[ct][1]) + (tA[ct][2]+tA[ct][3]);
    sB += (tB[ct][0]+tB[ct][1]) + (tB[ct][2]+tB[ct][3]);
  }
  sA += __shfl_xor(sA, 16, 64); sA += __shfl_xor(sA, 32, 64);
  sB += __shfl_xor(sB, 16, 64); sB += __shfl_xor(sB, 32, 64);
  float muA = sA * (1.f/64.f), muB = sB * (1.f/64.f);
  float vA = 0.f, vB = 0.f;
  #pragma unroll
  for (int ct = 0; ct < 4; ++ct){
    #pragma unroll
    for (int rg = 0; rg < 4; ++rg){
      float dA = tA[ct][rg] - muA; vA += dA*dA;
      float dB = tB[ct][rg] - muB; vB += dB*dB;
    }
  }
  vA += __shfl_xor(vA, 16, 64); vA += __shfl_xor(vA, 32, 64);
  vB += __shfl_xor(vB, 16, 64); vB += __shfl_xor(vB, 32, 64);
  float rsA = rsqrtf(vA * (1.f/64.f) + 1e-5f);
  float rsB = rsqrtf(vB * (1.f/64.f) + 1e-5f);
  #pragma unroll
  for (int ct = 0; ct < 4; ++ct){
    float4 g4 = *(const float4*)(g_ln + ct*16 + 4*g);
    float4 bb = *(const float4*)(b_ln + ct*16 + 4*g);
    float4 oA;
    oA.x = g4.x*(tA[ct][0]-muA)*rsA + bb.x;
    oA.y = g4.y*(tA[ct][1]-muA)*rsA + bb.y;
    oA.z = g4.z*(tA[ct][2]-muA)*rsA + bb.z;
    oA.w = g4.w*(tA[ct][3]-muA)*rsA + bb.w;
    *(float4*)(out + (size_t)rowA * 64 + ct*16 + 4*g) = oA;
    if (bvB){
      float4 oB;
      oB.x = g4.x*(tB[ct][0]-muB)*rsB + bb.x;
      oB.y = g4.y*(tB[ct][1]-muB)*rsB + bb.y;
      oB.z = g4.z*(tB[ct][2]-muB)*rsB + bb.z;
      oB.w = g4.w*(tB[ct][3]-muB)*rsB + bb.w;
      *(float4*)(out + (size_t)rowB * 64 + ct*16 + 4*g) = oB;
    }
  }
}

extern "C" void kernel_launch(void* const* d_in, const int* in_sizes, int n_in,
                              void* d_out, int out_size, void* d_ws, size_t ws_size,
                              hipStream_t stream) {
  const float* x    = (const float*)d_in[0];
  const float* A    = (const float*)d_in[1];
  const float* AT   = (const float*)d_in[2];
  const float* Wq   = (const float*)d_in[3];
  const float* bq   = (const float*)d_in[4];
  const float* Wk   = (const float*)d_in[5];
  const float* bk   = (const float*)d_in[6];
  const float* Wks  = (const float*)d_in[7];
  const float* bks  = (const float*)d_in[8];
  const float* Wv   = (const float*)d_in[9];
  const float* bv   = (const float*)d_in[10];
  const float* Wvs  = (const float*)d_in[11];
  const float* bvs  = (const float*)d_in[12];
  const float* Wdi  = (const float*)d_in[13];
  const float* Wdo  = (const float*)d_in[14];
  const float* Wf1  = (const float*)d_in[15];
  const float* bf1  = (const float*)d_in[16];
  const float* Wf2  = (const float*)d_in[17];
  const float* bf2  = (const float*)d_in[18];
  const float* g_ln = (const float*)d_in[19];
  const float* b_ln = (const float*)d_in[20];
  float* out = (float*)d_out;

  float* ws = (float*)d_ws;
  ushort* proj  = (ushort*)ws;                     // 12 slots (Q,KS,VS): 11,980,800 ush
  float*  biasF = ws + 5990400;                    // 473,088 f [4][21][11][4][16][8]
  ushort* val   = (ushort*)(ws + 6463488);         // 3,993,600 ush
  ushort* vt    = (ushort*)(ws + 8460288);         // 4,325,376 ush [4][192][11][16][32]
  ushort* kperm = (ushort*)(ws + 10622976);        // 4,325,376 ush [4][192][11][2][16][16]
  ushort* Wcat  = (ushort*)(ws + 12785664);        // 28,672 ush
  float*  bcat  = ws + 12800000;                   // 320 f
  ushort* Wf1b  = Wcat + 320*64;
  ushort* Wf2b  = Wcat + 384*64;

  wpack_kernel<<<7, 256, 0, stream>>>(Wq, bq, Wk, bk, Wks, bks,
                                      Wv, bv, Wvs, bvs, Wf1, Wf2, Wcat, bcat);
  prep_kernel<<<NPB + NBIAS + NPAD, 256, 0, stream>>>(
      x, Wcat, bcat, proj, vt, kperm, Wdi, Wdo, A, AT, biasF);
  attn_kernel<<<ANB, 256, 0, stream>>>(proj, biasF, vt, kperm, val);
  ffn_kernel<<<FNB, 256, 0, stream>>>(val, x, Wf1b, bf1, Wf2b, bf2,
                                      g_ln, b_ln, out);
}